// Round 4
// baseline (212.510 us; speedup 1.0000x reference)
//
#include <hip/hip_runtime.h>

#define B1C   0.9f
#define B2C   0.999f

typedef float v2f __attribute__((ext_vector_type(2)));

__device__ __forceinline__ v2f splat(float s) { v2f r; r.x = s; r.y = s; return r; }

__device__ __forceinline__ float rlane(float v, int l) {
  return __int_as_float(__builtin_amdgcn_readlane(__float_as_int(v), l));
}

template <int CTRL, int RMASK, bool BC>
__device__ __forceinline__ float dpp_add(float x) {
  int y = __builtin_amdgcn_update_dpp(0, __float_as_int(x), CTRL, RMASK, 0xF, BC);
  return x + __int_as_float(y);
}

// x + x[lane^16], replicated (full-rate VALU permlane swap; no LDS pipe)
__device__ __forceinline__ float addx16(float x) {
#if __has_builtin(__builtin_amdgcn_permlane16_swap)
  unsigned xi = __float_as_uint(x);
  auto a = __builtin_amdgcn_permlane16_swap(xi, xi, false, false);
  return __uint_as_float(a[0]) + __uint_as_float(a[1]);
#else
  return x + __int_as_float(__builtin_amdgcn_ds_swizzle(__float_as_int(x), 0x401F));
#endif
}

// x + x[lane^32], replicated
__device__ __forceinline__ float addx32(float x) {
#if __has_builtin(__builtin_amdgcn_permlane32_swap)
  unsigned xi = __float_as_uint(x);
  auto b = __builtin_amdgcn_permlane32_swap(xi, xi, false, false);
  return __uint_as_float(b[0]) + __uint_as_float(b[1]);
#else
  int a32 = ((((int)threadIdx.x & 63) ^ 32) << 2);
  return x + __int_as_float(__builtin_amdgcn_ds_bpermute(a32, __float_as_int(x)));
#endif
}

// cross-row butterfly sum over lanes {l, l^16, l^32, l^48}
__device__ __forceinline__ float xrow_sum1(float x) {
  return addx32(addx16(x));
}

// 16-lane row reduction of 6 values, REPLICATED in all 16 lanes.
// One asm block of exactly 24 v_add_f32_dpp (row_ror 1/2/4/8), interleaved
// 6-wide so each value's next DPP read is 5 instructions after its write
// (>= 2 wait states, the gfx9 VALU->DPP hazard). Leading s_nop 1 covers the
// producer immediately preceding the block. This guarantees 1 instr per
// dpp-add (the update_dpp builtin can legalize to mov0+mov_dpp+add).
#define ROWSUM6(a0, a1, a2, a3, a4, a5)                                      \
  asm volatile(                                                              \
    "s_nop 1\n\t"                                                            \
    "v_add_f32_dpp %0, %0, %0 row_ror:1 row_mask:0xf bank_mask:0xf\n\t"      \
    "v_add_f32_dpp %1, %1, %1 row_ror:1 row_mask:0xf bank_mask:0xf\n\t"      \
    "v_add_f32_dpp %2, %2, %2 row_ror:1 row_mask:0xf bank_mask:0xf\n\t"      \
    "v_add_f32_dpp %3, %3, %3 row_ror:1 row_mask:0xf bank_mask:0xf\n\t"      \
    "v_add_f32_dpp %4, %4, %4 row_ror:1 row_mask:0xf bank_mask:0xf\n\t"      \
    "v_add_f32_dpp %5, %5, %5 row_ror:1 row_mask:0xf bank_mask:0xf\n\t"      \
    "v_add_f32_dpp %0, %0, %0 row_ror:2 row_mask:0xf bank_mask:0xf\n\t"      \
    "v_add_f32_dpp %1, %1, %1 row_ror:2 row_mask:0xf bank_mask:0xf\n\t"      \
    "v_add_f32_dpp %2, %2, %2 row_ror:2 row_mask:0xf bank_mask:0xf\n\t"      \
    "v_add_f32_dpp %3, %3, %3 row_ror:2 row_mask:0xf bank_mask:0xf\n\t"      \
    "v_add_f32_dpp %4, %4, %4 row_ror:2 row_mask:0xf bank_mask:0xf\n\t"      \
    "v_add_f32_dpp %5, %5, %5 row_ror:2 row_mask:0xf bank_mask:0xf\n\t"      \
    "v_add_f32_dpp %0, %0, %0 row_ror:4 row_mask:0xf bank_mask:0xf\n\t"      \
    "v_add_f32_dpp %1, %1, %1 row_ror:4 row_mask:0xf bank_mask:0xf\n\t"      \
    "v_add_f32_dpp %2, %2, %2 row_ror:4 row_mask:0xf bank_mask:0xf\n\t"      \
    "v_add_f32_dpp %3, %3, %3 row_ror:4 row_mask:0xf bank_mask:0xf\n\t"      \
    "v_add_f32_dpp %4, %4, %4 row_ror:4 row_mask:0xf bank_mask:0xf\n\t"      \
    "v_add_f32_dpp %5, %5, %5 row_ror:4 row_mask:0xf bank_mask:0xf\n\t"      \
    "v_add_f32_dpp %0, %0, %0 row_ror:8 row_mask:0xf bank_mask:0xf\n\t"      \
    "v_add_f32_dpp %1, %1, %1 row_ror:8 row_mask:0xf bank_mask:0xf\n\t"      \
    "v_add_f32_dpp %2, %2, %2 row_ror:8 row_mask:0xf bank_mask:0xf\n\t"      \
    "v_add_f32_dpp %3, %3, %3 row_ror:8 row_mask:0xf bank_mask:0xf\n\t"      \
    "v_add_f32_dpp %4, %4, %4 row_ror:8 row_mask:0xf bank_mask:0xf\n\t"      \
    "v_add_f32_dpp %5, %5, %5 row_ror:8 row_mask:0xf bank_mask:0xf"          \
    : "+v"(a0), "+v"(a1), "+v"(a2), "+v"(a3), "+v"(a4), "+v"(a5))

// full-wave sum replicated (enc_kernel only; not perf-critical)
__device__ __forceinline__ float wave_sum_repl(float x) {
  x = dpp_add<0x111, 0xF, true>(x);
  x = dpp_add<0x112, 0xF, true>(x);
  x = dpp_add<0x114, 0xF, true>(x);
  x = dpp_add<0x118, 0xF, true>(x);
  x = dpp_add<0x142, 0xa, false>(x);
  x = dpp_add<0x143, 0xc, false>(x);
  return rlane(x, 63);
}

// ---------------- K1: encode table for the 64 distinct tokens ----------------
__global__ void enc_kernel(
    const float* __restrict__ embed,
    const float* __restrict__ ff_w1, const float* __restrict__ ff_b1,
    const float* __restrict__ ff_w2, const float* __restrict__ ff_b2,
    const float* __restrict__ ln_g, const float* __restrict__ ln_b,
    const float* __restrict__ scorer_w,
    float* __restrict__ enc, float* __restrict__ sAt, float* __restrict__ sBt)
{
  const int b = blockIdx.x;      // token id
  const int lane = threadIdx.x;  // feature

  float e = embed[b * 64 + lane];
  float acc0 = ff_b1[lane], acc1 = ff_b1[64 + lane];
  #pragma unroll
  for (int j = 0; j < 64; ++j) {
    float ej = rlane(e, j);
    acc0 = fmaf(ej, ff_w1[j * 128 + lane], acc0);
    acc1 = fmaf(ej, ff_w1[j * 128 + 64 + lane], acc1);
  }
  acc0 = fmaxf(acc0, 0.f);
  acc1 = fmaxf(acc1, 0.f);

  float f = ff_b2[lane];
  #pragma unroll
  for (int l = 0; l < 64; ++l) {
    f = fmaf(rlane(acc0, l), ff_w2[l * 64 + lane], f);
    f = fmaf(rlane(acc1, l), ff_w2[(l + 64) * 64 + lane], f);
  }

  float x = e + f;
  float mu = wave_sum_repl(x) * (1.f / 64.f);
  float d = x - mu;
  float var = wave_sum_repl(d * d) * (1.f / 64.f);
  float h = d * (1.f / sqrtf(var + 1e-5f)) * ln_g[lane] + ln_b[lane];
  enc[b * 64 + lane] = h;

  float sa = wave_sum_repl(h * scorer_w[lane]);
  float sb = wave_sum_repl(h * scorer_w[64 + lane]);
  if (lane == 0) { sAt[b] = sa; sBt[b] = sb; }
}

// ---------------- Adam, scaled-state form ----------------
// M = m/(1-b1), V = v/(1-b2); V init 1e-27 replaces the eps/clamp.
__device__ __forceinline__ void adam2(v2f& p, v2f& M, v2f& V, v2f g, float lre) {
  M = __builtin_elementwise_fma(M, splat(B1C), g);
  V = __builtin_elementwise_fma(V, splat(B2C), g * g);
  v2f r; r.x = __builtin_amdgcn_rsqf(V.x);
         r.y = __builtin_amdgcn_rsqf(V.y);
  p = __builtin_elementwise_fma(M * r, splat(-lre), p);
}

// ---------------- K2: ONE wave per sample, 16 feat-lanes x 4 unit-rows ------
__global__ __launch_bounds__(256) __attribute__((amdgpu_waves_per_eu(2, 2)))
void adam_kernel(
    const int* __restrict__ seqs, const float* __restrict__ enc,
    const float* __restrict__ sAt, const float* __restrict__ sBt,
    const float* __restrict__ mlp_w1, const float* __restrict__ mlp_b1,
    const float* __restrict__ mlp_w2, const float* __restrict__ mlp_b2,
    const float* __restrict__ out_w, const float* __restrict__ out_b,
    float* __restrict__ out)
{
  const int wid  = threadIdx.x >> 6;
  const int lane = threadIdx.x & 63;
  const int fl = lane & 15, ug = lane >> 4;
  const int c0 = 6 * ug, jb = 4 * fl;
  const int sample = blockIdx.x * 4 + wid;

  // LRE[t] = 0.005*rc1[t]/sqrt(0.001*rc2[t]), t=1..8
  constexpr float LRE[8] = {0.05f, 0.0372068f, 0.0319407f, 0.0290564f,
                            0.0272746f, 0.0261060f, 0.0253188f, 0.0247876f};
  constexpr float VINIT = 1e-27f;

  int tv = seqs[sample * 32 + (lane & 31)];

  // scores -> sortable uint keys. scorer_b dropped: a uniform additive
  // constant cannot change argmin order (monotone key map). Key bit-twiddle
  // done on SALU after readfirstlane.
  unsigned skey[15]; int ta[15], tb[15];
  #pragma unroll
  for (int p = 0; p < 15; ++p) {
    ta[p] = __builtin_amdgcn_readlane(tv, 2 * p);
    tb[p] = __builtin_amdgcn_readlane(tv, 2 * p + 1);
    float sf = sAt[ta[p]] + sBt[tb[p]];
    int si = __builtin_amdgcn_readfirstlane(__float_as_int(sf));
    unsigned u = (unsigned)si;
    skey[p] = u ^ (((unsigned)(si >> 31)) | 0x80000000u);
  }
  int q30 = __builtin_amdgcn_readlane(tv, 30);

  // evict-min; strict < keeps FIRST min (all SALU)
  unsigned bs[8]; int bka[8], bva[8];
  #pragma unroll
  for (int i = 0; i < 8; ++i) { bs[i] = skey[i]; bka[i] = ta[i]; bva[i] = tb[i]; }
  #pragma unroll
  for (int n = 0; n < 7; ++n) {
    int mi = 0; unsigned ms = bs[0];
    #pragma unroll
    for (int i = 1; i < 8; ++i) {
      if (bs[i] < ms) { mi = i; ms = bs[i]; }
    }
    #pragma unroll
    for (int i = 0; i < 7; ++i) {
      bool sh = i >= mi;
      bs[i]  = sh ? bs[i + 1]  : bs[i];
      bka[i] = sh ? bka[i + 1] : bka[i];
      bva[i] = sh ? bva[i + 1] : bva[i];
    }
    bs[7] = skey[8 + n]; bka[7] = ta[8 + n]; bva[7] = tb[8 + n];
  }

  const float flm = (fl == 0) ? 1.f : 0.f;   // bias-owner masks
  const float ugm = (ug == 0) ? 1.f : 0.f;
  const float S = 2.f / 64.f;

  // ---- params: direct float2 (v2f) loads — all pairs are even-offset ----
  v2f w1p[4][3], mw1[4][3], vw1[4][3];
  #pragma unroll
  for (int m = 0; m < 4; ++m) {
    const v2f* src = (const v2f*)(mlp_w1 + (jb + m) * 24 + c0);
    #pragma unroll
    for (int p = 0; p < 3; ++p) {
      w1p[m][p] = src[p]; mw1[m][p] = splat(0.f); vw1[m][p] = splat(VINIT);
    }
  }
  v2f w2p[6][2], mw2[6][2], vw2[6][2];
  #pragma unroll
  for (int cc = 0; cc < 6; ++cc) {
    const v2f* src = (const v2f*)(mlp_w2 + (c0 + cc) * 64 + jb);
    #pragma unroll
    for (int p = 0; p < 2; ++p) {
      w2p[cc][p] = src[p]; mw2[cc][p] = splat(0.f); vw2[cc][p] = splat(VINIT);
    }
  }
  v2f b1p[3], mb1[3], vb1[3];
  {
    const v2f* src = (const v2f*)(mlp_b1 + c0);
    #pragma unroll
    for (int p = 0; p < 3; ++p) {
      b1p[p] = src[p] * splat(flm); mb1[p] = splat(0.f); vb1[p] = splat(VINIT);
    }
  }
  v2f b2p[2], mb2[2], vb2[2];
  {
    const v2f* src = (const v2f*)(mlp_b2 + jb);
    #pragma unroll
    for (int p = 0; p < 2; ++p) {
      b2p[p] = src[p] * splat(ugm); mb2[p] = splat(0.f); vb2[p] = splat(VINIT);
    }
  }

  // rolling prefetch of (k,v) rows; v pre-scaled by -S (so dout = fma(po,S,vn))
  float4 kf = *(const float4*)(enc + bka[0] * 64 + jb);
  float4 vf = *(const float4*)(enc + bva[0] * 64 + jb);
  v2f vn[2];
  vn[0].x = vf.x * -S; vn[0].y = vf.y * -S;
  vn[1].x = vf.z * -S; vn[1].y = vf.w * -S;

  #pragma unroll
  for (int step = 0; step < 8; ++step) {
    const int nidx = (step < 7) ? step + 1 : 7;
    float4 kfn = *(const float4*)(enc + bka[nidx] * 64 + jb);
    float4 vfn = *(const float4*)(enc + bva[nidx] * 64 + jb);

    const float lre = LRE[step];
    const float km[4] = {kf.x, kf.y, kf.z, kf.w};

    // layer1: t2[p] = b1p[p] + sum_m k_m * w1p[m][p]
    v2f t2[3] = {b1p[0], b1p[1], b1p[2]};
    #pragma unroll
    for (int m = 0; m < 4; ++m) {
      v2f km2 = splat(km[m]);
      #pragma unroll
      for (int p = 0; p < 3; ++p) t2[p] = __builtin_elementwise_fma(km2, w1p[m][p], t2[p]);
    }
    float t0 = t2[0].x, t1 = t2[0].y, t3 = t2[1].x, t4 = t2[1].y,
          t5 = t2[2].x, t6 = t2[2].y;
    ROWSUM6(t0, t1, t3, t4, t5, t6);              // replicated in all row lanes
    float asw[6] = {fmaxf(t0, 0.f), fmaxf(t1, 0.f), fmaxf(t3, 0.f),
                    fmaxf(t4, 0.f), fmaxf(t5, 0.f), fmaxf(t6, 0.f)};

    // layer2 partials (2-branch tree to halve the dependency chain)
    v2f po2[2];
    #pragma unroll
    for (int p = 0; p < 2; ++p) {
      v2f e0 = b2p[p], e1 = splat(asw[3]) * w2p[3][p];
      e0 = __builtin_elementwise_fma(splat(asw[0]), w2p[0][p], e0);
      e1 = __builtin_elementwise_fma(splat(asw[4]), w2p[4][p], e1);
      e0 = __builtin_elementwise_fma(splat(asw[1]), w2p[1][p], e0);
      e1 = __builtin_elementwise_fma(splat(asw[5]), w2p[5][p], e1);
      e0 = __builtin_elementwise_fma(splat(asw[2]), w2p[2][p], e0);
      po2[p] = e0 + e1;
    }
    // cross-row sum: permlane butterfly, no DS ops
    #pragma unroll
    for (int p = 0; p < 2; ++p) {
      po2[p].x = xrow_sum1(po2[p].x);
      po2[p].y = xrow_sum1(po2[p].y);
    }
    v2f dout2[2];
    #pragma unroll
    for (int p = 0; p < 2; ++p)
      dout2[p] = __builtin_elementwise_fma(po2[p], splat(S), vn[p]);

    // dh[cc] over own 4 j, then row-reduce (replicated) + relu' gate
    float dh[6];
    #pragma unroll
    for (int cc = 0; cc < 6; ++cc) {
      v2f q = w2p[cc][0] * dout2[0];
      q = __builtin_elementwise_fma(w2p[cc][1], dout2[1], q);
      dh[cc] = q.x + q.y;
    }
    ROWSUM6(dh[0], dh[1], dh[2], dh[3], dh[4], dh[5]);
    float dpre[6];
    #pragma unroll
    for (int cc = 0; cc < 6; ++cc)
      dpre[cc] = (asw[cc] > 0.f) ? dh[cc] : 0.f;
    v2f dpre2[3]; dpre2[0].x = dpre[0]; dpre2[0].y = dpre[1];
                  dpre2[1].x = dpre[2]; dpre2[1].y = dpre[3];
                  dpre2[2].x = dpre[4]; dpre2[2].y = dpre[5];

    // Adam updates
    #pragma unroll
    for (int m = 0; m < 4; ++m) {
      v2f km2 = splat(km[m]);
      #pragma unroll
      for (int p = 0; p < 3; ++p)
        adam2(w1p[m][p], mw1[m][p], vw1[m][p], km2 * dpre2[p], lre);
    }
    #pragma unroll
    for (int cc = 0; cc < 6; ++cc) {
      v2f a2 = splat(asw[cc]);
      #pragma unroll
      for (int p = 0; p < 2; ++p)
        adam2(w2p[cc][p], mw2[cc][p], vw2[cc][p], a2 * dout2[p], lre);
    }
    #pragma unroll
    for (int p = 0; p < 3; ++p)
      adam2(b1p[p], mb1[p], vb1[p], dpre2[p] * splat(flm), lre);
    #pragma unroll
    for (int p = 0; p < 2; ++p)
      adam2(b2p[p], mb2[p], vb2[p], dout2[p] * splat(ugm), lre);

    kf = kfn;
    vn[0].x = vfn.x * -S; vn[0].y = vfn.y * -S;
    vn[1].x = vfn.z * -S; vn[1].y = vfn.w * -S;
  }

  // ---- query: enc[tok30] through finetuned MLP ----
  float4 qf = *(const float4*)(enc + q30 * 64 + jb);
  const float qm[4] = {qf.x, qf.y, qf.z, qf.w};
  v2f t2[3] = {b1p[0], b1p[1], b1p[2]};
  #pragma unroll
  for (int m = 0; m < 4; ++m) {
    v2f km2 = splat(qm[m]);
    #pragma unroll
    for (int p = 0; p < 3; ++p) t2[p] = __builtin_elementwise_fma(km2, w1p[m][p], t2[p]);
  }
  float t0 = t2[0].x, t1 = t2[0].y, t3 = t2[1].x, t4 = t2[1].y,
        t5 = t2[2].x, t6 = t2[2].y;
  ROWSUM6(t0, t1, t3, t4, t5, t6);
  float asw[6] = {fmaxf(t0, 0.f), fmaxf(t1, 0.f), fmaxf(t3, 0.f),
                  fmaxf(t4, 0.f), fmaxf(t5, 0.f), fmaxf(t6, 0.f)};
  v2f po2[2];
  #pragma unroll
  for (int p = 0; p < 2; ++p) {
    v2f e0 = b2p[p], e1 = splat(asw[3]) * w2p[3][p];
    e0 = __builtin_elementwise_fma(splat(asw[0]), w2p[0][p], e0);
    e1 = __builtin_elementwise_fma(splat(asw[4]), w2p[4][p], e1);
    e0 = __builtin_elementwise_fma(splat(asw[1]), w2p[1][p], e0);
    e1 = __builtin_elementwise_fma(splat(asw[5]), w2p[5][p], e1);
    e0 = __builtin_elementwise_fma(splat(asw[2]), w2p[2][p], e0);
    po2[p] = e0 + e1;
  }
  #pragma unroll
  for (int p = 0; p < 2; ++p) {
    po2[p].x = xrow_sum1(po2[p].x);
    po2[p].y = xrow_sum1(po2[p].y);
  }
  float po[4] = {po2[0].x, po2[0].y, po2[1].x, po2[1].y};
  // y_{4f+m} = po[m] @ lane f (replicated across rows)

  // ---- output head: lane = output column; 4 accumulators to cut the chain ----
  float ac0 = out_b[lane], ac1 = 0.f, ac2 = 0.f, ac3 = 0.f;
  #pragma unroll
  for (int l = 0; l < 64; l += 4) {
    ac0 = fmaf(rlane(po[0], l >> 2), out_w[(l    ) * 64 + lane], ac0);
    ac1 = fmaf(rlane(po[1], l >> 2), out_w[(l + 1) * 64 + lane], ac1);
    ac2 = fmaf(rlane(po[2], l >> 2), out_w[(l + 2) * 64 + lane], ac2);
    ac3 = fmaf(rlane(po[3], l >> 2), out_w[(l + 3) * 64 + lane], ac3);
  }
  out[(size_t)sample * 64 + lane] = (ac0 + ac1) + (ac2 + ac3);
}

extern "C" void kernel_launch(void* const* d_in, const int* in_sizes, int n_in,
                              void* d_out, int out_size, void* d_ws, size_t ws_size,
                              hipStream_t stream) {
  const int*   seqs     = (const int*)d_in[0];
  const float* embed    = (const float*)d_in[1];
  const float* ff_w1    = (const float*)d_in[2];
  const float* ff_b1    = (const float*)d_in[3];
  const float* ff_w2    = (const float*)d_in[4];
  const float* ff_b2    = (const float*)d_in[5];
  const float* ln_g     = (const float*)d_in[6];
  const float* ln_b     = (const float*)d_in[7];
  const float* scorer_w = (const float*)d_in[8];
  const float* mlp_w1   = (const float*)d_in[10];
  const float* mlp_b1   = (const float*)d_in[11];
  const float* mlp_w2   = (const float*)d_in[12];
  const float* mlp_b2   = (const float*)d_in[13];
  const float* out_w    = (const float*)d_in[14];
  const float* out_b    = (const float*)d_in[15];

  const int B = in_sizes[0] / 32;        // 16384
  float* enc = (float*)d_ws;             // 64*64 floats = 16 KB
  float* sAt = enc + 64 * 64;            // 64 floats
  float* sBt = sAt + 64;                 // 64 floats

  enc_kernel<<<64, 64, 0, stream>>>(embed, ff_w1, ff_b1, ff_w2, ff_b2,
                                    ln_g, ln_b, scorer_w, enc, sAt, sBt);
  adam_kernel<<<B / 4, 256, 0, stream>>>(seqs, enc, sAt, sBt,
                                         mlp_w1, mlp_b1, mlp_w2, mlp_b2,
                                         out_w, out_b, (float*)d_out);
}

// Round 7
// 208.439 us; speedup vs baseline: 1.0195x; 1.0195x over previous
//
#include <hip/hip_runtime.h>

#define B1C   0.9f
#define B2C   0.999f

typedef float v2f __attribute__((ext_vector_type(2)));

__device__ __forceinline__ v2f splat(float s) { v2f r; r.x = s; r.y = s; return r; }

__device__ __forceinline__ float rlane(float v, int l) {
  return __int_as_float(__builtin_amdgcn_readlane(__float_as_int(v), l));
}

template <int CTRL, int RMASK, bool BC>
__device__ __forceinline__ float dpp_add(float x) {
  int y = __builtin_amdgcn_update_dpp(0, __float_as_int(x), CTRL, RMASK, 0xF, BC);
  return x + __int_as_float(y);
}

// x + x[lane^16], replicated (full-rate VALU permlane swap; no LDS pipe)
__device__ __forceinline__ float addx16(float x) {
#if __has_builtin(__builtin_amdgcn_permlane16_swap)
  unsigned xi = __float_as_uint(x);
  auto a = __builtin_amdgcn_permlane16_swap(xi, xi, false, false);
  return __uint_as_float(a[0]) + __uint_as_float(a[1]);
#else
  return x + __int_as_float(__builtin_amdgcn_ds_swizzle(__float_as_int(x), 0x401F));
#endif
}

// x + x[lane^32], replicated
__device__ __forceinline__ float addx32(float x) {
#if __has_builtin(__builtin_amdgcn_permlane32_swap)
  unsigned xi = __float_as_uint(x);
  auto b = __builtin_amdgcn_permlane32_swap(xi, xi, false, false);
  return __uint_as_float(b[0]) + __uint_as_float(b[1]);
#else
  int a32 = ((((int)threadIdx.x & 63) ^ 32) << 2);
  return x + __int_as_float(__builtin_amdgcn_ds_bpermute(a32, __float_as_int(x)));
#endif
}

// cross-row butterfly sum over lanes {l, l^16, l^32, l^48}
__device__ __forceinline__ float xrow_sum1(float x) {
  return addx32(addx16(x));
}

// 16-lane row reduction of 6 values, REPLICATED in all 16 lanes.
// 24 v_add_f32_dpp (row_ror 1/2/4/8), 6-wide interleave covers the DPP
// read-after-VALU-write hazard internally; s_nop 1 covers the producer.
#define ROWSUM6(a0, a1, a2, a3, a4, a5)                                      \
  asm volatile(                                                              \
    "s_nop 1\n\t"                                                            \
    "v_add_f32_dpp %0, %0, %0 row_ror:1 row_mask:0xf bank_mask:0xf\n\t"      \
    "v_add_f32_dpp %1, %1, %1 row_ror:1 row_mask:0xf bank_mask:0xf\n\t"      \
    "v_add_f32_dpp %2, %2, %2 row_ror:1 row_mask:0xf bank_mask:0xf\n\t"      \
    "v_add_f32_dpp %3, %3, %3 row_ror:1 row_mask:0xf bank_mask:0xf\n\t"      \
    "v_add_f32_dpp %4, %4, %4 row_ror:1 row_mask:0xf bank_mask:0xf\n\t"      \
    "v_add_f32_dpp %5, %5, %5 row_ror:1 row_mask:0xf bank_mask:0xf\n\t"      \
    "v_add_f32_dpp %0, %0, %0 row_ror:2 row_mask:0xf bank_mask:0xf\n\t"      \
    "v_add_f32_dpp %1, %1, %1 row_ror:2 row_mask:0xf bank_mask:0xf\n\t"      \
    "v_add_f32_dpp %2, %2, %2 row_ror:2 row_mask:0xf bank_mask:0xf\n\t"      \
    "v_add_f32_dpp %3, %3, %3 row_ror:2 row_mask:0xf bank_mask:0xf\n\t"      \
    "v_add_f32_dpp %4, %4, %4 row_ror:2 row_mask:0xf bank_mask:0xf\n\t"      \
    "v_add_f32_dpp %5, %5, %5 row_ror:2 row_mask:0xf bank_mask:0xf\n\t"      \
    "v_add_f32_dpp %0, %0, %0 row_ror:4 row_mask:0xf bank_mask:0xf\n\t"      \
    "v_add_f32_dpp %1, %1, %1 row_ror:4 row_mask:0xf bank_mask:0xf\n\t"      \
    "v_add_f32_dpp %2, %2, %2 row_ror:4 row_mask:0xf bank_mask:0xf\n\t"      \
    "v_add_f32_dpp %3, %3, %3 row_ror:4 row_mask:0xf bank_mask:0xf\n\t"      \
    "v_add_f32_dpp %4, %4, %4 row_ror:4 row_mask:0xf bank_mask:0xf\n\t"      \
    "v_add_f32_dpp %5, %5, %5 row_ror:4 row_mask:0xf bank_mask:0xf\n\t"      \
    "v_add_f32_dpp %0, %0, %0 row_ror:8 row_mask:0xf bank_mask:0xf\n\t"      \
    "v_add_f32_dpp %1, %1, %1 row_ror:8 row_mask:0xf bank_mask:0xf\n\t"      \
    "v_add_f32_dpp %2, %2, %2 row_ror:8 row_mask:0xf bank_mask:0xf\n\t"      \
    "v_add_f32_dpp %3, %3, %3 row_ror:8 row_mask:0xf bank_mask:0xf\n\t"      \
    "v_add_f32_dpp %4, %4, %4 row_ror:8 row_mask:0xf bank_mask:0xf\n\t"      \
    "v_add_f32_dpp %5, %5, %5 row_ror:8 row_mask:0xf bank_mask:0xf"          \
    : "+v"(a0), "+v"(a1), "+v"(a2), "+v"(a3), "+v"(a4), "+v"(a5))

// full-wave sum replicated (enc_kernel only; not perf-critical)
__device__ __forceinline__ float wave_sum_repl(float x) {
  x = dpp_add<0x111, 0xF, true>(x);
  x = dpp_add<0x112, 0xF, true>(x);
  x = dpp_add<0x114, 0xF, true>(x);
  x = dpp_add<0x118, 0xF, true>(x);
  x = dpp_add<0x142, 0xa, false>(x);
  x = dpp_add<0x143, 0xc, false>(x);
  return rlane(x, 63);
}

// ---------------- K1: encode table for the 64 distinct tokens ----------------
// 4 waves per token-block: each wave computes a 16-term partial of both
// inner dot loops; LDS reduce (2 barriers). Cuts the serial loop depth 4x —
// the old 64x64 launch had 1 wave/SIMD on 6% of the GPU with zero latency
// hiding.
__global__ __launch_bounds__(256) void enc_kernel(
    const float* __restrict__ embed,
    const float* __restrict__ ff_w1, const float* __restrict__ ff_b1,
    const float* __restrict__ ff_w2, const float* __restrict__ ff_b2,
    const float* __restrict__ ln_g, const float* __restrict__ ln_b,
    const float* __restrict__ scorer_w,
    float* __restrict__ enc, float* __restrict__ sAt, float* __restrict__ sBt)
{
  const int b = blockIdx.x;          // token id
  const int tid = threadIdx.x;
  const int lane = tid & 63;         // feature
  const int w = tid >> 6;            // wave 0..3
  const int j0 = w * 16;

  __shared__ float red0[4][64];
  __shared__ float red1[4][64];

  float e = embed[b * 64 + lane];

  float acc0 = (w == 0) ? ff_b1[lane] : 0.f;
  float acc1 = (w == 0) ? ff_b1[64 + lane] : 0.f;
  #pragma unroll
  for (int jj = 0; jj < 16; ++jj) {
    int j = j0 + jj;
    float ej = rlane(e, j);
    acc0 = fmaf(ej, ff_w1[j * 128 + lane], acc0);
    acc1 = fmaf(ej, ff_w1[j * 128 + 64 + lane], acc1);
  }
  red0[w][lane] = acc0;
  red1[w][lane] = acc1;
  __syncthreads();
  acc0 = (red0[0][lane] + red0[1][lane]) + (red0[2][lane] + red0[3][lane]);
  acc1 = (red1[0][lane] + red1[1][lane]) + (red1[2][lane] + red1[3][lane]);
  acc0 = fmaxf(acc0, 0.f);
  acc1 = fmaxf(acc1, 0.f);

  float f = (w == 0) ? ff_b2[lane] : 0.f;
  #pragma unroll
  for (int ll = 0; ll < 16; ++ll) {
    int l = j0 + ll;
    f = fmaf(rlane(acc0, l), ff_w2[l * 64 + lane], f);
    f = fmaf(rlane(acc1, l), ff_w2[(l + 64) * 64 + lane], f);
  }
  __syncthreads();               // all reads of red0/red1 done before rewrite
  red0[w][lane] = f;
  __syncthreads();

  if (w == 0) {
    f = (red0[0][lane] + red0[1][lane]) + (red0[2][lane] + red0[3][lane]);
    float x = e + f;
    float mu = wave_sum_repl(x) * (1.f / 64.f);
    float d = x - mu;
    float var = wave_sum_repl(d * d) * (1.f / 64.f);
    float h = d * (1.f / sqrtf(var + 1e-5f)) * ln_g[lane] + ln_b[lane];
    enc[b * 64 + lane] = h;

    float sa = wave_sum_repl(h * scorer_w[lane]);
    float sb = wave_sum_repl(h * scorer_w[64 + lane]);
    if (lane == 0) { sAt[b] = sa; sBt[b] = sb; }
  }
}

// ---------------- Adam, scaled-state form ----------------
// M = m/(1-b1), V = v/(1-b2); V init 1e-27 replaces the eps/clamp.
__device__ __forceinline__ void adam2(v2f& p, v2f& M, v2f& V, v2f g, float lre) {
  M = __builtin_elementwise_fma(M, splat(B1C), g);
  V = __builtin_elementwise_fma(V, splat(B2C), g * g);
  v2f r; r.x = __builtin_amdgcn_rsqf(V.x);
         r.y = __builtin_amdgcn_rsqf(V.y);
  p = __builtin_elementwise_fma(M * r, splat(-lre), p);
}

// ---------------- K2: ONE wave per sample, 16 feat-lanes x 4 unit-rows ------
__global__ __launch_bounds__(256) __attribute__((amdgpu_waves_per_eu(2, 2)))
void adam_kernel(
    const int* __restrict__ seqs, const float* __restrict__ enc,
    const float* __restrict__ sAt, const float* __restrict__ sBt,
    const float* __restrict__ mlp_w1, const float* __restrict__ mlp_b1,
    const float* __restrict__ mlp_w2, const float* __restrict__ mlp_b2,
    const float* __restrict__ out_w, const float* __restrict__ out_b,
    float* __restrict__ out)
{
  const int wid  = threadIdx.x >> 6;
  const int lane = threadIdx.x & 63;
  const int fl = lane & 15, ug = lane >> 4;
  const int c0 = 6 * ug, jb = 4 * fl;
  const int sample = blockIdx.x * 4 + wid;

  // LRE[t] = 0.005*rc1[t]/sqrt(0.001*rc2[t]), t=1..8
  constexpr float LRE[8] = {0.05f, 0.0372068f, 0.0319407f, 0.0290564f,
                            0.0272746f, 0.0261060f, 0.0253188f, 0.0247876f};
  constexpr float VINIT = 1e-27f;

  int tv = seqs[sample * 32 + (lane & 31)];

  // scores -> sortable uint keys. scorer_b dropped (monotone key map).
  unsigned skey[15]; int ta[15], tb[15];
  #pragma unroll
  for (int p = 0; p < 15; ++p) {
    ta[p] = __builtin_amdgcn_readlane(tv, 2 * p);
    tb[p] = __builtin_amdgcn_readlane(tv, 2 * p + 1);
    float sf = sAt[ta[p]] + sBt[tb[p]];
    int si = __builtin_amdgcn_readfirstlane(__float_as_int(sf));
    unsigned u = (unsigned)si;
    skey[p] = u ^ (((unsigned)(si >> 31)) | 0x80000000u);
  }
  int q30 = __builtin_amdgcn_readlane(tv, 30);

  // evict-min; strict < keeps FIRST min (all SALU)
  unsigned bs[8]; int bka[8], bva[8];
  #pragma unroll
  for (int i = 0; i < 8; ++i) { bs[i] = skey[i]; bka[i] = ta[i]; bva[i] = tb[i]; }
  #pragma unroll
  for (int n = 0; n < 7; ++n) {
    int mi = 0; unsigned ms = bs[0];
    #pragma unroll
    for (int i = 1; i < 8; ++i) {
      if (bs[i] < ms) { mi = i; ms = bs[i]; }
    }
    #pragma unroll
    for (int i = 0; i < 7; ++i) {
      bool sh = i >= mi;
      bs[i]  = sh ? bs[i + 1]  : bs[i];
      bka[i] = sh ? bka[i + 1] : bka[i];
      bva[i] = sh ? bva[i + 1] : bva[i];
    }
    bs[7] = skey[8 + n]; bka[7] = ta[8 + n]; bva[7] = tb[8 + n];
  }

  const float flm = (fl == 0) ? 1.f : 0.f;   // bias-owner masks
  const float ugm = (ug == 0) ? 1.f : 0.f;
  const float S = 2.f / 64.f;

  // ---- params: direct float2 (v2f) loads — all pairs are even-offset ----
  v2f w1p[4][3], mw1[4][3], vw1[4][3];
  #pragma unroll
  for (int m = 0; m < 4; ++m) {
    const v2f* src = (const v2f*)(mlp_w1 + (jb + m) * 24 + c0);
    #pragma unroll
    for (int p = 0; p < 3; ++p) {
      w1p[m][p] = src[p]; mw1[m][p] = splat(0.f); vw1[m][p] = splat(VINIT);
    }
  }
  v2f w2p[6][2], mw2[6][2], vw2[6][2];
  #pragma unroll
  for (int cc = 0; cc < 6; ++cc) {
    const v2f* src = (const v2f*)(mlp_w2 + (c0 + cc) * 64 + jb);
    #pragma unroll
    for (int p = 0; p < 2; ++p) {
      w2p[cc][p] = src[p]; mw2[cc][p] = splat(0.f); vw2[cc][p] = splat(VINIT);
    }
  }
  v2f b1p[3], mb1[3], vb1[3];
  {
    const v2f* src = (const v2f*)(mlp_b1 + c0);
    #pragma unroll
    for (int p = 0; p < 3; ++p) {
      b1p[p] = src[p] * splat(flm); mb1[p] = splat(0.f); vb1[p] = splat(VINIT);
    }
  }
  v2f b2p[2], mb2[2], vb2[2];
  {
    const v2f* src = (const v2f*)(mlp_b2 + jb);
    #pragma unroll
    for (int p = 0; p < 2; ++p) {
      b2p[p] = src[p] * splat(ugm); mb2[p] = splat(0.f); vb2[p] = splat(VINIT);
    }
  }

  // rolling prefetch of (k,v) rows; v pre-scaled by -S (so dout = fma(po,S,vn))
  float4 kf = *(const float4*)(enc + bka[0] * 64 + jb);
  float4 vf = *(const float4*)(enc + bva[0] * 64 + jb);
  v2f vn[2];
  vn[0].x = vf.x * -S; vn[0].y = vf.y * -S;
  vn[1].x = vf.z * -S; vn[1].y = vf.w * -S;

  #pragma unroll
  for (int step = 0; step < 8; ++step) {
    const int nidx = (step < 7) ? step + 1 : 7;
    float4 kfn = *(const float4*)(enc + bka[nidx] * 64 + jb);
    float4 vfn = *(const float4*)(enc + bva[nidx] * 64 + jb);

    const float lre = LRE[step];
    const float km[4] = {kf.x, kf.y, kf.z, kf.w};

    // layer1: t2[p] = b1p[p] + sum_m k_m * w1p[m][p]
    v2f t2[3] = {b1p[0], b1p[1], b1p[2]};
    #pragma unroll
    for (int m = 0; m < 4; ++m) {
      v2f km2 = splat(km[m]);
      #pragma unroll
      for (int p = 0; p < 3; ++p) t2[p] = __builtin_elementwise_fma(km2, w1p[m][p], t2[p]);
    }
    float t0 = t2[0].x, t1 = t2[0].y, t3 = t2[1].x, t4 = t2[1].y,
          t5 = t2[2].x, t6 = t2[2].y;
    ROWSUM6(t0, t1, t3, t4, t5, t6);              // replicated in all row lanes
    float asw[6] = {fmaxf(t0, 0.f), fmaxf(t1, 0.f), fmaxf(t3, 0.f),
                    fmaxf(t4, 0.f), fmaxf(t5, 0.f), fmaxf(t6, 0.f)};

    // layer2 partials (2-branch tree to halve the dependency chain)
    v2f po2[2];
    #pragma unroll
    for (int p = 0; p < 2; ++p) {
      v2f e0 = b2p[p], e1 = splat(asw[3]) * w2p[3][p];
      e0 = __builtin_elementwise_fma(splat(asw[0]), w2p[0][p], e0);
      e1 = __builtin_elementwise_fma(splat(asw[4]), w2p[4][p], e1);
      e0 = __builtin_elementwise_fma(splat(asw[1]), w2p[1][p], e0);
      e1 = __builtin_elementwise_fma(splat(asw[5]), w2p[5][p], e1);
      e0 = __builtin_elementwise_fma(splat(asw[2]), w2p[2][p], e0);
      po2[p] = e0 + e1;
    }
    // cross-row sum: permlane butterfly, no DS ops
    #pragma unroll
    for (int p = 0; p < 2; ++p) {
      po2[p].x = xrow_sum1(po2[p].x);
      po2[p].y = xrow_sum1(po2[p].y);
    }
    v2f dout2[2];
    #pragma unroll
    for (int p = 0; p < 2; ++p)
      dout2[p] = __builtin_elementwise_fma(po2[p], splat(S), vn[p]);

    // dh[cc] over own 4 j, then row-reduce (replicated) + relu' gate
    float dh[6];
    #pragma unroll
    for (int cc = 0; cc < 6; ++cc) {
      v2f q = w2p[cc][0] * dout2[0];
      q = __builtin_elementwise_fma(w2p[cc][1], dout2[1], q);
      dh[cc] = q.x + q.y;
    }
    ROWSUM6(dh[0], dh[1], dh[2], dh[3], dh[4], dh[5]);
    float dpre[6];
    #pragma unroll
    for (int cc = 0; cc < 6; ++cc)
      dpre[cc] = (asw[cc] > 0.f) ? dh[cc] : 0.f;
    v2f dpre2[3]; dpre2[0].x = dpre[0]; dpre2[0].y = dpre[1];
                  dpre2[1].x = dpre[2]; dpre2[1].y = dpre[3];
                  dpre2[2].x = dpre[4]; dpre2[2].y = dpre[5];

    // Adam updates
    #pragma unroll
    for (int m = 0; m < 4; ++m) {
      v2f km2 = splat(km[m]);
      #pragma unroll
      for (int p = 0; p < 3; ++p)
        adam2(w1p[m][p], mw1[m][p], vw1[m][p], km2 * dpre2[p], lre);
    }
    #pragma unroll
    for (int cc = 0; cc < 6; ++cc) {
      v2f a2 = splat(asw[cc]);
      #pragma unroll
      for (int p = 0; p < 2; ++p)
        adam2(w2p[cc][p], mw2[cc][p], vw2[cc][p], a2 * dout2[p], lre);
    }
    #pragma unroll
    for (int p = 0; p < 3; ++p)
      adam2(b1p[p], mb1[p], vb1[p], dpre2[p] * splat(flm), lre);
    #pragma unroll
    for (int p = 0; p < 2; ++p)
      adam2(b2p[p], mb2[p], vb2[p], dout2[p] * splat(ugm), lre);

    kf = kfn;
    vn[0].x = vfn.x * -S; vn[0].y = vfn.y * -S;
    vn[1].x = vfn.z * -S; vn[1].y = vfn.w * -S;
  }

  // ---- query: enc[tok30] through finetuned MLP ----
  float4 qf = *(const float4*)(enc + q30 * 64 + jb);
  const float qm[4] = {qf.x, qf.y, qf.z, qf.w};
  v2f t2[3] = {b1p[0], b1p[1], b1p[2]};
  #pragma unroll
  for (int m = 0; m < 4; ++m) {
    v2f km2 = splat(qm[m]);
    #pragma unroll
    for (int p = 0; p < 3; ++p) t2[p] = __builtin_elementwise_fma(km2, w1p[m][p], t2[p]);
  }
  float t0 = t2[0].x, t1 = t2[0].y, t3 = t2[1].x, t4 = t2[1].y,
        t5 = t2[2].x, t6 = t2[2].y;
  ROWSUM6(t0, t1, t3, t4, t5, t6);
  float asw[6] = {fmaxf(t0, 0.f), fmaxf(t1, 0.f), fmaxf(t3, 0.f),
                  fmaxf(t4, 0.f), fmaxf(t5, 0.f), fmaxf(t6, 0.f)};
  v2f po2[2];
  #pragma unroll
  for (int p = 0; p < 2; ++p) {
    v2f e0 = b2p[p], e1 = splat(asw[3]) * w2p[3][p];
    e0 = __builtin_elementwise_fma(splat(asw[0]), w2p[0][p], e0);
    e1 = __builtin_elementwise_fma(splat(asw[4]), w2p[4][p], e1);
    e0 = __builtin_elementwise_fma(splat(asw[1]), w2p[1][p], e0);
    e1 = __builtin_elementwise_fma(splat(asw[5]), w2p[5][p], e1);
    e0 = __builtin_elementwise_fma(splat(asw[2]), w2p[2][p], e0);
    po2[p] = e0 + e1;
  }
  #pragma unroll
  for (int p = 0; p < 2; ++p) {
    po2[p].x = xrow_sum1(po2[p].x);
    po2[p].y = xrow_sum1(po2[p].y);
  }
  float po[4] = {po2[0].x, po2[0].y, po2[1].x, po2[1].y};
  // y_{4f+m} = po[m] @ lane f (replicated across rows)

  // ---- output head: lane = output column; 4 accumulators to cut the chain ----
  float ac0 = out_b[lane], ac1 = 0.f, ac2 = 0.f, ac3 = 0.f;
  #pragma unroll
  for (int l = 0; l < 64; l += 4) {
    ac0 = fmaf(rlane(po[0], l >> 2), out_w[(l    ) * 64 + lane], ac0);
    ac1 = fmaf(rlane(po[1], l >> 2), out_w[(l + 1) * 64 + lane], ac1);
    ac2 = fmaf(rlane(po[2], l >> 2), out_w[(l + 2) * 64 + lane], ac2);
    ac3 = fmaf(rlane(po[3], l >> 2), out_w[(l + 3) * 64 + lane], ac3);
  }
  out[(size_t)sample * 64 + lane] = (ac0 + ac1) + (ac2 + ac3);
}

extern "C" void kernel_launch(void* const* d_in, const int* in_sizes, int n_in,
                              void* d_out, int out_size, void* d_ws, size_t ws_size,
                              hipStream_t stream) {
  const int*   seqs     = (const int*)d_in[0];
  const float* embed    = (const float*)d_in[1];
  const float* ff_w1    = (const float*)d_in[2];
  const float* ff_b1    = (const float*)d_in[3];
  const float* ff_w2    = (const float*)d_in[4];
  const float* ff_b2    = (const float*)d_in[5];
  const float* ln_g     = (const float*)d_in[6];
  const float* ln_b     = (const float*)d_in[7];
  const float* scorer_w = (const float*)d_in[8];
  const float* mlp_w1   = (const float*)d_in[10];
  const float* mlp_b1   = (const float*)d_in[11];
  const float* mlp_w2   = (const float*)d_in[12];
  const float* mlp_b2   = (const float*)d_in[13];
  const float* out_w    = (const float*)d_in[14];
  const float* out_b    = (const float*)d_in[15];

  const int B = in_sizes[0] / 32;        // 16384
  float* enc = (float*)d_ws;             // 64*64 floats = 16 KB
  float* sAt = enc + 64 * 64;            // 64 floats
  float* sBt = sAt + 64;                 // 64 floats

  enc_kernel<<<64, 256, 0, stream>>>(embed, ff_w1, ff_b1, ff_w2, ff_b2,
                                     ln_g, ln_b, scorer_w, enc, sAt, sBt);
  adam_kernel<<<B / 4, 256, 0, stream>>>(seqs, enc, sAt, sBt,
                                         mlp_w1, mlp_b1, mlp_w2, mlp_b2,
                                         out_w, out_b, (float*)d_out);
}